// Round 7
// baseline (182.465 us; speedup 1.0000x reference)
//
#include <hip/hip_runtime.h>
#include <stdint.h>

#define N_BOX 8400
#define NCLS 80
#define PSTRIDE 85
#define NW 132            // 64-bit words covering 8400
#define NSB 33            // 256-box super-blocks
#define CONF_T 0.01f
#define NMS_T 0.2f

typedef unsigned long long u64;

// ws layout (bytes). diagd ALIASES det: det is dead after rank_k, diagd is
// written by mask_k (later) — lifetimes disjoint.
#define OFF_DET     0                    // 8400 x 8 f32   = 268800
#define OFF_DIAGD   0                    // 33*64*10 u64   = 168960 (alias, see above)
#define OFF_KEYS    268800               // 8400 u64       = 67200
#define OFF_DETS    336000               // 8400 x 8 f32   = 268800
#define OFF_BOXESS  604800               // 8400 float4    = 134400
#define OFF_MASK    739200               // 8400 x 132 u64 = 8870400 (16B aligned)
#define OFF_KEEPW   9609600              // 132 u64        = 1056
#define OFF_VCNT    9610656              // 1 int

__device__ __forceinline__ unsigned fmap_desc(float f) {
    unsigned u = __float_as_uint(f);
    unsigned m = (u & 0x80000000u) ? ~u : (u | 0x80000000u); // monotone ascending
    return ~m;                                               // descending
}

__device__ __forceinline__ u64 readlane64(u64 v, int lane) {
    unsigned lo = (unsigned)__builtin_amdgcn_readlane((int)(unsigned)v, lane);
    unsigned hi = (unsigned)__builtin_amdgcn_readlane((int)(unsigned)(v >> 32), lane);
    return ((u64)hi << 32) | lo;
}

__device__ __forceinline__ u64 wmask(int w, int V) {
    int nb = V - (w << 6);
    if (nb <= 0) return 0ull;
    if (nb >= 64) return ~0ull;
    return (1ull << nb) - 1ull;
}

__device__ __forceinline__ int nextbit4(u64& r0, u64& r1, u64& r2, u64& r3, int prev) {
    if (r0) { int b = __builtin_ctzll(r0); r0 &= r0 - 1; return b; }
    if (r1) { int b = __builtin_ctzll(r1); r1 &= r1 - 1; return 64 + b; }
    if (r2) { int b = __builtin_ctzll(r2); r2 &= r2 - 1; return 128 + b; }
    if (r3) { int b = __builtin_ctzll(r3); r3 &= r3 - 1; return 192 + b; }
    return prev;
}

// ---- kernel A: per-row preprocess, 4 lanes per row ----
__global__ __launch_bounds__(256) void prep_k(const float* __restrict__ pred,
                                              float* __restrict__ det,
                                              u64* __restrict__ keys) {
    int gt = blockIdx.x * 256 + threadIdx.x;
    int i = gt >> 2, q = gt & 3;
    if (i >= N_BOX) return;
    const float* p = pred + (size_t)i * PSTRIDE;
    int cbase = q * 20;
    float best = p[5 + cbase];
    int arg = cbase;
    for (int c = 1; c < 20; ++c) {
        float v = p[5 + cbase + c];
        if (v > best) { best = v; arg = cbase + c; }   // strict > : first max in segment
    }
    // quad-combine: larger value wins; tie -> smaller class index (numpy first-max)
    for (int d = 1; d < 4; d <<= 1) {
        float ob = __shfl_xor(best, d);
        int   oa = __shfl_xor(arg, d);
        if (ob > best || (ob == best && oa < arg)) { best = ob; arg = oa; }
    }
    if (q == 0) {
        float cx = p[0], cy = p[1], w = p[2], h = p[3], obj = p[4];
        float hw = __fmul_rn(w, 0.5f), hh = __fmul_rn(h, 0.5f);
        float x1 = __fsub_rn(cx, hw), y1 = __fsub_rn(cy, hh);
        float x2 = __fadd_rn(cx, hw), y2 = __fadd_rn(cy, hh);
        bool valid = (obj >= CONF_T);
        float score = valid ? obj : -1.0f;
        keys[i] = ((u64)fmap_desc(score) << 32) | (unsigned)i;
        float4* dr = (float4*)(det + (size_t)i * 8);
        dr[0] = make_float4(x1, y1, x2, y2);
        dr[1] = make_float4(obj, best, (float)arg, 0.0f);
    }
}

// ---- kernel B: rank + scatter. 32 keys/block, 8 j-slices, LDS reduce. ----
__global__ __launch_bounds__(256) void rank_k(const u64* __restrict__ keys,
                                              const float* __restrict__ det,
                                              float4* __restrict__ det_s,
                                              float4* __restrict__ boxes_s,
                                              int* __restrict__ vcount) {
    int t = threadIdx.x;
    int i = blockIdx.x * 32 + (t & 31);
    int s = t >> 5;                    // slice 0..7, 1050 keys each
    u64 my = (i < N_BOX) ? keys[i] : ~0ull;
    int cnt = 0, cv = 0;
    int j0 = s * 1050, j1 = j0 + 1050;
    for (int j = j0; j < j1; j += 2) {
        ulonglong2 kk = *(const ulonglong2*)(keys + j);
        cnt += (kk.x < my) + (kk.y < my);
        cv  += ((long long)kk.x >= 0) + ((long long)kk.y >= 0);
    }
    __shared__ int sc[256], sv[256];
    sc[t] = cnt; sv[t] = cv;
    __syncthreads();
    if (t < 32) {
        int r = sc[t] + sc[t + 32] + sc[t + 64] + sc[t + 96]
              + sc[t + 128] + sc[t + 160] + sc[t + 192] + sc[t + 224];
        if (i < N_BOX) {
            const float4* dr = (const float4*)(det + (size_t)i * 8);
            float4 b0 = dr[0], b1 = dr[1];
            det_s[(size_t)r * 2]     = b0;
            det_s[(size_t)r * 2 + 1] = b1;
            boxes_s[r] = b0;
        }
        if (blockIdx.x == 0 && t == 0) {
            *vcount = sv[0] + sv[32] + sv[64] + sv[96]
                    + sv[128] + sv[160] + sv[192] + sv[224];
        }
    }
}

// ---- kernel C: suppression bitmask, UPPER TRIANGLE ONLY (no zero-fill). ----
// Intra-super-block tiles are ALSO written densely to diagd for the scan:
// diagd[(W*64 + lane)*10 + ord(g,k)], ord enumerates k>=g upper-tri pairs.
__global__ __launch_bounds__(64) void mask_k(const float4* __restrict__ boxes_s,
                                             u64* __restrict__ mask,
                                             u64* __restrict__ diagd) {
    int tt = blockIdx.x, lane = threadIdx.x;
    // decode linear t -> (rb, cb), rb<=cb ; f(rb) = rb*NW - rb*(rb-1)/2
    int rb = (int)((2.0f * NW + 1.0f
                    - sqrtf((2.0f * NW + 1.0f) * (2.0f * NW + 1.0f) - 8.0f * (float)tt)) * 0.5f);
    while (rb > 0 && rb * NW - rb * (rb - 1) / 2 > tt) rb--;
    while ((rb + 1) * NW - (rb + 1) * rb / 2 <= tt) rb++;
    int cb = rb + (tt - (rb * NW - rb * (rb - 1) / 2));

    __shared__ float4 cB[64];
    __shared__ float  cA[64];
    int c0 = cb * 64 + lane;
    float4 b = (c0 < N_BOX) ? boxes_s[c0] : make_float4(0.f, 0.f, 0.f, 0.f);
    cB[lane] = b;
    cA[lane] = __fmul_rn(__fsub_rn(b.z, b.x), __fsub_rn(b.w, b.y));
    __syncthreads();
    int r = rb * 64 + lane;
    if (r >= N_BOX) return;
    float4 rx = boxes_s[r];
    float ra = __fmul_rn(__fsub_rn(rx.z, rx.x), __fsub_rn(rx.w, rx.y));
    u64 bits = 0ull;
    int cbase = cb * 64;
    for (int j = 0; j < 64; ++j) {
        int c = cbase + j;
        if (c >= N_BOX || c <= r) continue;
        float4 cx4 = cB[j];
        float ltx = fmaxf(rx.x, cx4.x), lty = fmaxf(rx.y, cx4.y);
        float rbx = fminf(rx.z, cx4.z), rby = fminf(rx.w, cx4.w);
        float wx = fmaxf(__fsub_rn(rbx, ltx), 0.0f);
        float wy = fmaxf(__fsub_rn(rby, lty), 0.0f);
        float inter = __fmul_rn(wx, wy);
        float denom = __fadd_rn(__fsub_rn(__fadd_rn(ra, cA[j]), inter), 1e-9f);
        float iou = __fdiv_rn(inter, denom);
        if (iou > NMS_T) bits |= (1ull << j);
    }
    mask[(size_t)r * NW + cb] = bits;
    int W2 = rb >> 2;
    if ((cb >> 2) == W2) {
        int g = rb & 3, k = cb & 3;
        int ord = g * 4 + k - ((g * (g + 1)) >> 1);
        diagd[((size_t)W2 * 64 + lane) * 10 + ord] = bits;
    }
}

// ---- scan helpers ----
// diag tile for super-block W, lane l: q{g}{k} = mask bits of row 256W+64g+l vs
// column word 4W+k, loaded DENSELY from diagd (5 coalesced ulonglong2 / lane).
__device__ __forceinline__ void load_diag(int W, int lane, const u64* __restrict__ diagd,
    u64& q00, u64& q01, u64& q02, u64& q03,
    u64& q11, u64& q12, u64& q13,
    u64& q22, u64& q23, u64& q33) {
    int Wc = W < NSB ? W : (NSB - 1);
    const u64* bp = diagd + ((size_t)Wc * 64 + lane) * 10;
    ulonglong2 v;
    v = *(const ulonglong2*)(bp + 0); q00 = v.x; q01 = v.y;
    v = *(const ulonglong2*)(bp + 2); q02 = v.x; q03 = v.y;
    v = *(const ulonglong2*)(bp + 4); q11 = v.x; q12 = v.y;
    v = *(const ulonglong2*)(bp + 6); q13 = v.x; q22 = v.y;
    v = *(const ulonglong2*)(bp + 8); q23 = v.x; q33 = v.y;
}

__device__ __forceinline__ void proc_sb(int W, int V, int lane,
    const u64* __restrict__ mask, u64* __restrict__ keepw,
    u64& Ra, u64& Rb, u64& Rc,
    u64 q00, u64 q01, u64 q02, u64 q03,
    u64 q11, u64 q12, u64 q13,
    u64 q22, u64 q23, u64 q33) {
    int wb = 4 * W;
    auto getremv = [&](int w) -> u64 {
        u64 rw = (w < 128) ? ((w & 1) ? Rb : Ra) : Rc;
        int sl = (w < 128) ? (w >> 1) : (w - 128);
        return readlane64(rw, sl);
    };
    u64 c0 = getremv(wb + 0), c1 = getremv(wb + 1);
    u64 c2 = getremv(wb + 2), c3 = getremv(wb + 3);
    u64 m0 = wmask(wb + 0, V), m1 = wmask(wb + 1, V);
    u64 m2 = wmask(wb + 2, V), m3 = wmask(wb + 3, V);
    u64 ns;
    ns = ~c0 & m0;                           // leaders in word 0 (group 0)
    while (ns) {
        int b = __builtin_ctzll(ns); ns &= ns - 1;
        u64 w0 = readlane64(q00, b), w1 = readlane64(q01, b);
        u64 w2 = readlane64(q02, b), w3 = readlane64(q03, b);
        c0 |= w0; c1 |= w1; c2 |= w2; c3 |= w3;
        ns &= ~w0;
    }
    ns = ~c1 & m1;                           // group 1: words 1..3 valid
    while (ns) {
        int b = __builtin_ctzll(ns); ns &= ns - 1;
        u64 w1 = readlane64(q11, b), w2 = readlane64(q12, b), w3 = readlane64(q13, b);
        c1 |= w1; c2 |= w2; c3 |= w3;
        ns &= ~w1;
    }
    ns = ~c2 & m2;                           // group 2: words 2..3 valid
    while (ns) {
        int b = __builtin_ctzll(ns); ns &= ns - 1;
        u64 w2 = readlane64(q22, b), w3 = readlane64(q23, b);
        c2 |= w2; c3 |= w3;
        ns &= ~w2;
    }
    ns = ~c3 & m3;                           // group 3: word 3 valid
    while (ns) {
        int b = __builtin_ctzll(ns); ns &= ns - 1;
        u64 w3 = readlane64(q33, b);
        c3 |= w3;
        ns &= ~w3;
    }
    u64 a0 = ~c0 & m0, a1 = ~c1 & m1, a2 = ~c2 & m2, a3 = ~c3 & m3;
    if (lane == 0) {
        keepw[wb + 0] = a0; keepw[wb + 1] = a1;
        keepw[wb + 2] = a2; keepw[wb + 3] = a3;
    }
    // batch-OR alive rows, 16 rows per wait (48 loads in flight).
    // Lane word-pair clamp: lanes l < 2W would read words < wb — those bits are
    // lower-triangle poison AND their remv words are already consumed/keepw'd,
    // so clamp them all to one broadcast address (word pair wb) to save lines.
    int rbase = 256 * W;
    int tw = (lane < 4) ? (128 + lane) : 131;
    int lpair = (lane < 2 * W) ? wb : (2 * lane);
    while (a0 | a1 | a2 | a3) {
        int g0  = nextbit4(a0, a1, a2, a3, 0);
        int g1  = nextbit4(a0, a1, a2, a3, g0);
        int g2  = nextbit4(a0, a1, a2, a3, g1);
        int g3  = nextbit4(a0, a1, a2, a3, g2);
        int g4  = nextbit4(a0, a1, a2, a3, g3);
        int g5  = nextbit4(a0, a1, a2, a3, g4);
        int g6  = nextbit4(a0, a1, a2, a3, g5);
        int g7  = nextbit4(a0, a1, a2, a3, g6);
        int g8  = nextbit4(a0, a1, a2, a3, g7);
        int g9  = nextbit4(a0, a1, a2, a3, g8);
        int g10 = nextbit4(a0, a1, a2, a3, g9);
        int g11 = nextbit4(a0, a1, a2, a3, g10);
        int g12 = nextbit4(a0, a1, a2, a3, g11);
        int g13 = nextbit4(a0, a1, a2, a3, g12);
        int g14 = nextbit4(a0, a1, a2, a3, g13);
        int g15 = nextbit4(a0, a1, a2, a3, g14);
        u64 A0,B0,T0, A1,B1,T1, A2,B2,T2, A3,B3,T3;
        u64 A4,B4,T4, A5,B5,T5, A6,B6,T6, A7,B7,T7;
        u64 A8,B8,T8, A9,B9,T9, A10,B10,T10, A11,B11,T11;
        u64 A12,B12,T12, A13,B13,T13, A14,B14,T14, A15,B15,T15;
#define ROWL(s, g) do {                                                  \
        const u64* rp_ = mask + (size_t)(rbase + (g)) * NW;              \
        ulonglong2 v_ = *(const ulonglong2*)(rp_ + lpair);               \
        A##s = v_.x; B##s = v_.y; T##s = rp_[tw];                        \
    } while (0)
        ROWL(0, g0);   ROWL(1, g1);   ROWL(2, g2);   ROWL(3, g3);
        ROWL(4, g4);   ROWL(5, g5);   ROWL(6, g6);   ROWL(7, g7);
        ROWL(8, g8);   ROWL(9, g9);   ROWL(10, g10); ROWL(11, g11);
        ROWL(12, g12); ROWL(13, g13); ROWL(14, g14); ROWL(15, g15);
#undef ROWL
        Ra |= ((A0|A1)|(A2|A3)) | ((A4|A5)|(A6|A7))
            | ((A8|A9)|(A10|A11)) | ((A12|A13)|(A14|A15));
        Rb |= ((B0|B1)|(B2|B3)) | ((B4|B5)|(B6|B7))
            | ((B8|B9)|(B10|B11)) | ((B12|B13)|(B14|B15));
        Rc |= ((T0|T1)|(T2|T3)) | ((T4|T5)|(T6|T7))
            | ((T8|T9)|(T10|T11)) | ((T12|T13)|(T14|T15));
    }
}

// ---- kernel D: block-wise greedy scan over 256-box super-blocks, one wave ----
__global__ __launch_bounds__(64) void scan_k(const u64* __restrict__ mask,
                                             const u64* __restrict__ diagd,
                                             const int* __restrict__ vcount,
                                             u64* __restrict__ keepw) {
    int lane = threadIdx.x;
    int V = *vcount;
    u64 Ra = 0ull, Rb = 0ull, Rc = 0ull;
    u64 q00,q01,q02,q03,q11,q12,q13,q22,q23,q33;
    u64 n00,n01,n02,n03,n11,n12,n13,n22,n23,n33;

#define LQ(P, W) load_diag((W), lane, diagd, P##00,P##01,P##02,P##03,   \
                           P##11,P##12,P##13, P##22,P##23, P##33)
#define PS(P, W) proc_sb((W), V, lane, mask, keepw, Ra, Rb, Rc,          \
                         P##00,P##01,P##02,P##03, P##11,P##12,P##13,     \
                         P##22,P##23, P##33)
    LQ(q, 0);
    int W = 0;
    for (; W + 1 < NSB; W += 2) {
        LQ(n, W + 1);
        PS(q, W);
        LQ(q, W + 2);
        PS(n, W + 1);
    }
    PS(q, W);            // W == 32 (NSB odd)
#undef LQ
#undef PS
}

// ---- kernel E: masked write-out (7 cols) ----
__global__ __launch_bounds__(256) void out_k(const float* __restrict__ det_s,
                                             const u64* __restrict__ keepw,
                                             float* __restrict__ out) {
    int e = blockIdx.x * 256 + threadIdx.x;
    if (e >= N_BOX * 7) return;
    int r = e / 7, c = e - r * 7;
    bool k = (keepw[r >> 6] >> (r & 63)) & 1ull;
    out[e] = k ? det_s[r * 8 + c] : 0.0f;
}

extern "C" void kernel_launch(void* const* d_in, const int* in_sizes, int n_in,
                              void* d_out, int out_size, void* d_ws, size_t ws_size,
                              hipStream_t stream) {
    const float* pred = (const float*)d_in[0];
    char* ws = (char*)d_ws;
    float*  det     = (float*) (ws + OFF_DET);
    u64*    diagd   = (u64*)   (ws + OFF_DIAGD);
    u64*    keys    = (u64*)   (ws + OFF_KEYS);
    float*  det_s   = (float*) (ws + OFF_DETS);
    float4* boxes_s = (float4*)(ws + OFF_BOXESS);
    u64*    mask    = (u64*)   (ws + OFF_MASK);
    u64*    keepw   = (u64*)   (ws + OFF_KEEPW);
    int*    vcount  = (int*)   (ws + OFF_VCNT);

    prep_k<<<132, 256, 0, stream>>>(pred, det, keys);
    rank_k<<<264, 256, 0, stream>>>(keys, det, (float4*)det_s, boxes_s, vcount);
    mask_k<<<NW * (NW + 1) / 2, 64, 0, stream>>>(boxes_s, mask, diagd);
    scan_k<<<1, 64, 0, stream>>>(mask, diagd, vcount, keepw);
    out_k <<<(N_BOX * 7 + 255) / 256, 256, 0, stream>>>(det_s, keepw, (float*)d_out);
}